// Round 6
// baseline (335.411 us; speedup 1.0000x reference)
//
#include <hip/hip_runtime.h>
#include <math.h>

// ---------------- problem constants ----------------
constexpr int NN1 = 65536;      // level-0 nodes
constexpr int EE  = 1048576;    // edges
constexpr int GG  = 64;         // graphs
constexpr int HH  = 128;        // hidden
constexpr int NPG = 1024;       // nodes/graph level-0
constexpr int EPG = 16384;      // edges/graph
constexpr int K1  = 512;        // keep after pool1 (per graph)
constexpr int M1  = GG * K1;    // 32768
constexpr int K2  = 256;        // keep after pool2
constexpr int M2  = GG * K2;    // 16384

__device__ __forceinline__ float4 f4add(float4 a, float4 b)
{
    a.x += b.x; a.y += b.y; a.z += b.z; a.w += b.w; return a;
}

// ---------------- GEMM: C[r] = scale[r] * (Asrc[r] @ W), fp32 ----------------
// 512 threads; tile 128 rows x 128 cols; thread: 4 rows x 8 cols -> 16 waves/CU.
// W staged in LDS in two 64-row chunks (40960 B); col-group cg (0..15) at float
// offset cg*10 in a 160-float row -> b128 starts at 16 distinct even bank residues,
// uniform 2-way aliasing (free on CDNA4). A loads software-pipelined.
// IX=true: row r sourced from A[perm[r]] and scaled by tsel[r] (SAGPool gather fused).
template <bool IX>
__global__ __launch_bounds__(512) void gemm_k(const float* __restrict__ A,
                                              const float* __restrict__ W,
                                              const int* __restrict__ rbeg,
                                              const int* __restrict__ rend,
                                              const int* __restrict__ perm,
                                              const float* __restrict__ tsel,
                                              float* __restrict__ C)
{
    __shared__ float Wl[64 * 160];   // 40960 B
    const int t    = threadIdx.x;
    const int cg   = t & 15;         // 0..15, col base cg*8
    const int rowg = t >> 4;         // 0..31
    const int r0   = (blockIdx.x << 7) + rowg;

    const float* Ap[4];
#pragma unroll
    for (int i = 0; i < 4; ++i) {
        int r = r0 + (i << 5);
        int s = IX ? perm[r] : r;
        Ap[i] = A + ((size_t)s << 7);
    }

    float acc[4][8];
#pragma unroll
    for (int i = 0; i < 4; ++i)
#pragma unroll
        for (int j = 0; j < 8; ++j) acc[i][j] = 0.f;

    // ---- stage chunk 0 (k = 0..63) ----
    {
        const float4* Wg = (const float4*)W;
#pragma unroll
        for (int i = 0; i < 4; ++i) {
            int idx = t + (i << 9);
            int k   = idx >> 5;
            int c4  = (idx & 31) << 2;
            *(float4*)&Wl[k * 160 + (c4 >> 3) * 10 + (c4 & 7)] = Wg[idx];
        }
    }
    float4 xc[4], xn[4];
#pragma unroll
    for (int i = 0; i < 4; ++i) xc[i] = *(const float4*)(Ap[i]);
    __syncthreads();

    const float* wb = &Wl[cg * 10];

#pragma unroll 1
    for (int k0 = 0; k0 < 64; k0 += 4) {
#pragma unroll
        for (int i = 0; i < 4; ++i) xn[i] = *(const float4*)(Ap[i] + k0 + 4);
#pragma unroll
        for (int kk = 0; kk < 4; ++kk) {
            const float* wr = wb + (k0 + kk) * 160;
            float wv[8];
            *(float4*)&wv[0] = *(const float4*)(wr);
            *(float4*)&wv[4] = *(const float4*)(wr + 4);
#pragma unroll
            for (int i = 0; i < 4; ++i) {
                float xv = ((const float*)&xc[i])[kk];
#pragma unroll
                for (int j = 0; j < 8; ++j) acc[i][j] = fmaf(xv, wv[j], acc[i][j]);
            }
        }
#pragma unroll
        for (int i = 0; i < 4; ++i) xc[i] = xn[i];
    }
    __syncthreads();
    // ---- stage chunk 1 (k = 64..127) ----
    {
        const float4* Wg = (const float4*)(W + 64 * 128);
#pragma unroll
        for (int i = 0; i < 4; ++i) {
            int idx = t + (i << 9);
            int k   = idx >> 5;
            int c4  = (idx & 31) << 2;
            *(float4*)&Wl[k * 160 + (c4 >> 3) * 10 + (c4 & 7)] = Wg[idx];
        }
    }
    __syncthreads();

#pragma unroll 1
    for (int k0 = 64; k0 < 128; k0 += 4) {
        bool pf = (k0 < 124);
        if (pf) {
#pragma unroll
            for (int i = 0; i < 4; ++i) xn[i] = *(const float4*)(Ap[i] + k0 + 4);
        }
#pragma unroll
        for (int kk = 0; kk < 4; ++kk) {
            const float* wr = wb + (k0 - 64 + kk) * 160;
            float wv[8];
            *(float4*)&wv[0] = *(const float4*)(wr);
            *(float4*)&wv[4] = *(const float4*)(wr + 4);
#pragma unroll
            for (int i = 0; i < 4; ++i) {
                float xv = ((const float*)&xc[i])[kk];
#pragma unroll
                for (int j = 0; j < 8; ++j) acc[i][j] = fmaf(xv, wv[j], acc[i][j]);
            }
        }
        if (pf) {
#pragma unroll
            for (int i = 0; i < 4; ++i) xc[i] = xn[i];
        }
    }

    // epilogue: scale by dinv[r] (and tsel[r] if IX), write
#pragma unroll
    for (int i = 0; i < 4; ++i) {
        int r = r0 + (i << 5);
        float deg = (float)(rend[r] - rbeg[r]) + 1.0f;
        float sc = 1.0f / sqrtf(deg);
        if (IX) sc *= tsel[r];
        float* cp = C + ((size_t)r << 7) + (cg << 3);
        float4 v0, v1;
        v0.x = acc[i][0] * sc; v0.y = acc[i][1] * sc; v0.z = acc[i][2] * sc; v0.w = acc[i][3] * sc;
        v1.x = acc[i][4] * sc; v1.y = acc[i][5] * sc; v1.z = acc[i][6] * sc; v1.w = acc[i][7] * sc;
        *(float4*)(cp) = v0;
        *(float4*)(cp + 4) = v1;
    }
}

// ---------------- per-graph CSR build, level 1 (count+scan+fill in one block) ----------
__global__ __launch_bounds__(1024) void build_csr1_k(const int* __restrict__ src, const int* __restrict__ dst,
                                                     int* __restrict__ rbeg, int* __restrict__ rend,
                                                     int* __restrict__ csr)
{
    __shared__ int cnt[NPG];
    int t = threadIdx.x, g = blockIdx.x;
    int ebase = g * EPG;
    cnt[t] = 0;
    __syncthreads();
#pragma unroll
    for (int k = 0; k < EPG / 1024; ++k) {
        int d = dst[ebase + t + k * 1024] & (NPG - 1);
        atomicAdd(&cnt[d], 1);
    }
    __syncthreads();
    int deg0 = cnt[t];
    int val = deg0;
    for (int off = 1; off < NPG; off <<= 1) {
        int u = (t >= off) ? cnt[t - off] : 0;
        __syncthreads();
        val += u; cnt[t] = val;
        __syncthreads();
    }
    int node = g * NPG + t;
    rbeg[node] = ebase + val - deg0;
    rend[node] = ebase + val;
    cnt[t] = val - deg0;
    __syncthreads();
#pragma unroll
    for (int k = 0; k < EPG / 1024; ++k) {
        int e = ebase + t + k * 1024;
        int d = dst[e] & (NPG - 1);
        int pos = atomicAdd(&cnt[d], 1);
        csr[ebase + pos] = src[e];
    }
}

// ---------------- per-graph CSR build, level 2 (prune via nmap, remap ids) -------------
__global__ __launch_bounds__(1024) void build_csr2_k(const int* __restrict__ src, const int* __restrict__ dst,
                                                     const int* __restrict__ nmap,
                                                     int* __restrict__ rbeg, int* __restrict__ rend,
                                                     int* __restrict__ csr)
{
    __shared__ int cnt[K1];
    int t = threadIdx.x, g = blockIdx.x;
    int ebase = g * EPG;
    if (t < K1) cnt[t] = 0;
    __syncthreads();
    int ns[EPG / 1024], nd[EPG / 1024];
#pragma unroll
    for (int k = 0; k < EPG / 1024; ++k) {
        int e = ebase + t + k * 1024;
        ns[k] = nmap[src[e]];
        nd[k] = nmap[dst[e]];
        if (ns[k] >= 0 && nd[k] >= 0) atomicAdd(&cnt[nd[k] & (K1 - 1)], 1);
    }
    __syncthreads();
    int deg0 = 0, val = 0;
    if (t < K1) { deg0 = cnt[t]; val = deg0; }
    for (int off = 1; off < K1; off <<= 1) {
        int u = (t < K1 && t >= off) ? cnt[t - off] : 0;
        __syncthreads();
        if (t < K1) { val += u; cnt[t] = val; }
        __syncthreads();
    }
    if (t < K1) {
        int node = g * K1 + t;
        rbeg[node] = ebase + val - deg0;
        rend[node] = ebase + val;
        cnt[t] = val - deg0;
    }
    __syncthreads();
#pragma unroll
    for (int k = 0; k < EPG / 1024; ++k) {
        if (ns[k] >= 0 && nd[k] >= 0) {
            int pos = atomicAdd(&cnt[nd[k] & (K1 - 1)], 1);
            csr[ebase + pos] = ns[k];
        }
    }
}

// ---------------- GCN aggregation over prescaled rows, fused bias+relu+score-projection ----
// half-wave (32 lanes) per node, float4 per lane; dinv from rbeg/rend; XCD swizzle.
__global__ __launch_bounds__(256) void agg_feat_k(const float4* __restrict__ XWs,
                                                  const int* __restrict__ rbeg, const int* __restrict__ rend,
                                                  const int* __restrict__ csr,
                                                  const float* __restrict__ bias, const float* __restrict__ Ws,
                                                  float* __restrict__ hout, float* __restrict__ hss, int n)
{
    int nblk = gridDim.x;                       // multiple of 8
    int bid  = blockIdx.x;
    int b    = (bid & 7) * (nblk >> 3) + (bid >> 3);   // XCD chunk swizzle
    int half = threadIdx.x >> 5;
    int lane = threadIdx.x & 31;
    int node = (b << 3) + half;
    if (node >= n) return;
    const float4* Xf = XWs + lane;              // row r at Xf[r*32]

    float4 A = make_float4(0.f, 0.f, 0.f, 0.f), B = A, C = A, D = A;
    int p0 = rbeg[node], p1 = rend[node];
    int p = p0;
    for (; p + 8 <= p1; p += 8) {
        int s0 = csr[p], s1 = csr[p + 1], s2 = csr[p + 2], s3 = csr[p + 3];
        int s4 = csr[p + 4], s5 = csr[p + 5], s6 = csr[p + 6], s7 = csr[p + 7];
        float4 v0 = Xf[(size_t)s0 << 5], v1 = Xf[(size_t)s1 << 5];
        float4 v2 = Xf[(size_t)s2 << 5], v3 = Xf[(size_t)s3 << 5];
        float4 v4 = Xf[(size_t)s4 << 5], v5 = Xf[(size_t)s5 << 5];
        float4 v6 = Xf[(size_t)s6 << 5], v7 = Xf[(size_t)s7 << 5];
        A = f4add(A, v0); B = f4add(B, v1); C = f4add(C, v2); D = f4add(D, v3);
        A = f4add(A, v4); B = f4add(B, v5); C = f4add(C, v6); D = f4add(D, v7);
    }
    for (; p + 4 <= p1; p += 4) {
        int s0 = csr[p], s1 = csr[p + 1], s2 = csr[p + 2], s3 = csr[p + 3];
        float4 v0 = Xf[(size_t)s0 << 5], v1 = Xf[(size_t)s1 << 5];
        float4 v2 = Xf[(size_t)s2 << 5], v3 = Xf[(size_t)s3 << 5];
        A = f4add(A, v0); B = f4add(B, v1); C = f4add(C, v2); D = f4add(D, v3);
    }
    for (; p < p1; ++p) {
        int s = csr[p];
        A = f4add(A, Xf[(size_t)s << 5]);
    }
    float4 acc = f4add(f4add(A, B), f4add(C, D));
    acc = f4add(acc, Xf[(size_t)node << 5]);    // self term (prescaled)

    float dd = 1.0f / sqrtf((float)(p1 - p0) + 1.0f);
    float4 bb = *(const float4*)(bias + (lane << 2));
    acc.x = fmaxf(fmaf(acc.x, dd, bb.x), 0.f);
    acc.y = fmaxf(fmaf(acc.y, dd, bb.y), 0.f);
    acc.z = fmaxf(fmaf(acc.z, dd, bb.z), 0.f);
    acc.w = fmaxf(fmaf(acc.w, dd, bb.w), 0.f);
    *(float4*)(hout + ((size_t)node << 7) + (lane << 2)) = acc;

    float4 wsv = *(const float4*)(Ws + (lane << 2));
    float pq = acc.x * wsv.x + acc.y * wsv.y + acc.z * wsv.z + acc.w * wsv.w;
#pragma unroll
    for (int off = 16; off > 0; off >>= 1) pq += __shfl_down(pq, off, 32);
    if (lane == 0) hss[node] = dd * pq;         // prescaled score
}

// ---------------- fused score + per-graph top-k (+ nmap, + tanh(score)) -----------------
template <int NNE, int KK, bool MARK>
__global__ void sctopk_k(const int* __restrict__ rbeg, const int* __restrict__ rend,
                         const int* __restrict__ csr, const float* __restrict__ hss,
                         const float* __restrict__ bsp,
                         int* __restrict__ perm, float* __restrict__ tsel,
                         int* __restrict__ nmap)
{
    __shared__ unsigned long long keys[NNE];
    int t = threadIdx.x, g = blockIdx.x;
    int node = g * NNE + t;
    int p0 = rbeg[node], p1 = rend[node];
    float a = 0.f, b = 0.f, c = 0.f, e = 0.f;
    int p = p0;
    for (; p + 8 <= p1; p += 8) {
        int s0 = csr[p], s1 = csr[p + 1], s2 = csr[p + 2], s3 = csr[p + 3];
        int s4 = csr[p + 4], s5 = csr[p + 5], s6 = csr[p + 6], s7 = csr[p + 7];
        a += hss[s0]; b += hss[s1]; c += hss[s2]; e += hss[s3];
        a += hss[s4]; b += hss[s5]; c += hss[s6]; e += hss[s7];
    }
    for (; p + 4 <= p1; p += 4) {
        int s0 = csr[p], s1 = csr[p + 1], s2 = csr[p + 2], s3 = csr[p + 3];
        a += hss[s0]; b += hss[s1]; c += hss[s2]; e += hss[s3];
    }
    for (; p < p1; ++p) a += hss[csr[p]];
    float dd = 1.0f / sqrtf((float)(p1 - p0) + 1.0f);
    float s = fmaf((a + b) + (c + e) + hss[node], dd, bsp[0]);

    unsigned u = __float_as_uint(s);
    u = (u & 0x80000000u) ? ~u : (u | 0x80000000u);           // monotone map
    keys[t] = (((unsigned long long)u) << 32) | (unsigned)(NNE - 1 - t);
    __syncthreads();
    for (int k = 2; k <= NNE; k <<= 1) {
        for (int j = k >> 1; j > 0; j >>= 1) {
            int ixj = t ^ j;
            if (ixj > t) {
                unsigned long long ka = keys[t], kb = keys[ixj];
                bool up = ((t & k) == 0);
                if ((ka > kb) == up) { keys[t] = kb; keys[ixj] = ka; }
            }
            __syncthreads();
        }
    }
    unsigned long long key = keys[NNE - 1 - t];   // rank t
    int idx = NNE - 1 - (int)(key & 0xFFFFFFFFu);
    if (t < KK) {
        perm[g * KK + t] = g * NNE + idx;
        unsigned uu = (unsigned)(key >> 32);
        float sc = __uint_as_float((uu & 0x80000000u) ? (uu ^ 0x80000000u) : ~uu);
        tsel[g * KK + t] = tanhf(sc);
        if (MARK) nmap[g * NNE + idx] = g * KK + t;
    } else if (MARK) {
        nmap[g * NNE + idx] = -1;
    }
}

// ---------------- readout partials over gathered rows: per-128-node chunk {max | sum} ---
__global__ __launch_bounds__(128) void readout_ix_k(const float* __restrict__ h,
                                                    const int* __restrict__ perm,
                                                    const float* __restrict__ tsel,
                                                    float* __restrict__ part)
{
    int b = blockIdx.x, t = threadIdx.x;
    int base = b * 128;
    float mx = -INFINITY, sm = 0.f;
#pragma unroll 4
    for (int r = 0; r < 128; ++r) {
        int o = perm[base + r];
        float tv = tsel[base + r];
        float v = h[((size_t)o << 7) + t] * tv;
        mx = fmaxf(mx, v);
        sm += v;
    }
    part[b * 256 + t] = mx;
    part[b * 256 + 128 + t] = sm;
}

// ---------------- head: combine partials; z=x1+x2; relu(z@Wl1+bl1); @Wl2+bl2 ------------
__global__ __launch_bounds__(128) void mlp_k(const float* __restrict__ part1, const float* __restrict__ part2,
                                             const float* __restrict__ Wl1, const float* __restrict__ bl1,
                                             const float* __restrict__ Wl2, const float* __restrict__ bl2,
                                             float* __restrict__ out)
{
    __shared__ float z[256];
    __shared__ float red[128];
    int g = blockIdx.x, t = threadIdx.x;
    float mx1 = -INFINITY, sm1 = 0.f;
#pragma unroll
    for (int j = 0; j < 4; ++j) {
        mx1 = fmaxf(mx1, part1[(g * 4 + j) * 256 + t]);
        sm1 += part1[(g * 4 + j) * 256 + 128 + t];
    }
    float mx2 = -INFINITY, sm2 = 0.f;
#pragma unroll
    for (int j = 0; j < 2; ++j) {
        mx2 = fmaxf(mx2, part2[(g * 2 + j) * 256 + t]);
        sm2 += part2[(g * 2 + j) * 256 + 128 + t];
    }
    z[t]       = mx1 + mx2;
    z[t + 128] = sm1 * (1.f / 512.f) + sm2 * (1.f / 256.f);
    __syncthreads();
    float acc = bl1[t];
    for (int k = 0; k < 256; ++k) acc = fmaf(z[k], Wl1[k * 128 + t], acc);
    float zz = fmaxf(acc, 0.f);
    red[t] = zz * Wl2[t];
    __syncthreads();
    for (int off = 64; off > 0; off >>= 1) {
        if (t < off) red[t] += red[t + off];
        __syncthreads();
    }
    if (t == 0) out[g] = red[0] + bl2[0];
}

// ---------------- launch ----------------
extern "C" void kernel_launch(void* const* d_in, const int* in_sizes, int n_in,
                              void* d_out, int out_size, void* d_ws, size_t ws_size,
                              hipStream_t stream)
{
    const float* x   = (const float*)d_in[0];
    const int*   src = (const int*)d_in[1];
    const int*   dst = (const int*)d_in[2];
    const float* W1  = (const float*)d_in[3];
    const float* b1  = (const float*)d_in[4];
    const float* Ws1 = (const float*)d_in[5];
    const float* bs1 = (const float*)d_in[6];
    const float* W2  = (const float*)d_in[7];
    const float* b2  = (const float*)d_in[8];
    const float* Ws2 = (const float*)d_in[9];
    const float* bs2 = (const float*)d_in[10];
    const float* Wl1 = (const float*)d_in[11];
    const float* bl1 = (const float*)d_in[12];
    const float* Wl2 = (const float*)d_in[13];
    const float* bl2 = (const float*)d_in[14];
    float* out = (float*)d_out;
    char* ws = (char*)d_ws;

    // big regions (time-multiplexed)
    float* XW1 = (float*)(ws);                        // 32MB [0,32M)   (dinv-prescaled)
    float* h1  = (float*)(ws + ((size_t)32 << 20));   // 32MB [32M,64M) (alive through readout_p1)
    float* XW2 = (float*)(ws);                        // 16MB [0,16M)   (XW1 dead after agg1)
    float* h2  = (float*)(ws + ((size_t)16 << 20));   // 16MB [16M,32M)
    size_t SB = (size_t)64 << 20;
    auto alloc = [&](size_t bytes) { char* p = ws + SB; SB += (bytes + 255) & ~(size_t)255; return p; };
    int* csr1     = (int*)alloc((size_t)EE * 4);      // reused as csr2 after sctopk1
    int* rbeg1    = (int*)alloc(NN1 * 4);
    int* rend1    = (int*)alloc(NN1 * 4);
    float* hss1   = (float*)alloc(NN1 * 4);
    int* nmap     = (int*)alloc(NN1 * 4);
    int* perm1    = (int*)alloc(M1 * 4);
    float* tsel1  = (float*)alloc(M1 * 4);
    int* rbeg2    = (int*)alloc(M1 * 4);
    int* rend2    = (int*)alloc(M1 * 4);
    float* hss2   = (float*)alloc(M1 * 4);
    int* perm2    = (int*)alloc(M2 * 4);
    float* tsel2  = (float*)alloc(M2 * 4);
    float* part1  = (float*)alloc(256 * 256 * 4);
    float* part2  = (float*)alloc(128 * 256 * 4);
    int* csr2     = csr1;
    (void)ws_size; (void)in_sizes; (void)n_in; (void)out_size;

    // ---- level 1 ----
    build_csr1_k<<<GG, 1024, 0, stream>>>(src, dst, rbeg1, rend1, csr1);
    gemm_k<false><<<NN1 / 128, 512, 0, stream>>>(x, W1, rbeg1, rend1, nullptr, nullptr, XW1);
    agg_feat_k<<<NN1 / 8, 256, 0, stream>>>((const float4*)XW1, rbeg1, rend1, csr1, b1, Ws1, h1, hss1, NN1);
    sctopk_k<NPG, K1, true><<<GG, NPG, 0, stream>>>(rbeg1, rend1, csr1, hss1, bs1, perm1, tsel1, nmap);
    // ---- level 2 ----
    build_csr2_k<<<GG, 1024, 0, stream>>>(src, dst, nmap, rbeg2, rend2, csr2);
    gemm_k<true><<<M1 / 128, 512, 0, stream>>>(h1, W2, rbeg2, rend2, perm1, tsel1, XW2);
    readout_ix_k<<<M1 / 128, 128, 0, stream>>>(h1, perm1, tsel1, part1);
    agg_feat_k<<<M1 / 8, 256, 0, stream>>>((const float4*)XW2, rbeg2, rend2, csr2, b2, Ws2, h2, hss2, M1);
    sctopk_k<K1, K2, false><<<GG, K1, 0, stream>>>(rbeg2, rend2, csr2, hss2, bs2, perm2, tsel2, nullptr);
    readout_ix_k<<<M2 / 128, 128, 0, stream>>>(h2, perm2, tsel2, part2);
    // ---- head ----
    mlp_k<<<GG, 128, 0, stream>>>(part1, part2, Wl1, bl1, Wl2, bl2, out);
}

// Round 7
// 334.263 us; speedup vs baseline: 1.0034x; 1.0034x over previous
//
#include <hip/hip_runtime.h>
#include <math.h>

// ---------------- problem constants ----------------
constexpr int NN1 = 65536;      // level-0 nodes
constexpr int EE  = 1048576;    // edges
constexpr int GG  = 64;         // graphs
constexpr int HH  = 128;        // hidden
constexpr int NPG = 1024;       // nodes/graph level-0
constexpr int EPG = 16384;      // edges/graph
constexpr int K1  = 512;        // keep after pool1 (per graph)
constexpr int M1  = GG * K1;    // 32768
constexpr int K2  = 256;        // keep after pool2
constexpr int M2  = GG * K2;    // 16384

__device__ __forceinline__ float4 f4add(float4 a, float4 b)
{
    a.x += b.x; a.y += b.y; a.z += b.z; a.w += b.w; return a;
}

// ---------------- GEMM: C[r] = scale[r] * (Asrc[r] @ W), fp32 ----------------
// 512 threads; tile 128 rows x 128 cols; thread: 4 rows x 8 cols.
// ALL of W staged once in LDS (81920 B, row stride 160) -> LDS-implied occupancy is
// exactly 2 blocks/CU = 16 waves/CU = 4 waves/SIMD -> backend VGPR cap 128 (no spill;
// R6's 40960B LDS implied 8 waves/SIMD -> cap 64 -> spilled, 125us). Single barrier.
// Col-group cg (0..15) at float offset cg*10: 16 distinct even bank residues,
// 4-way same-address broadcast within wave, max 2-way bank aliasing (free).
// IX=true: row r sourced from A[perm[r]] and scaled by tsel[r] (SAGPool gather fused).
template <bool IX>
__global__ __launch_bounds__(512) void gemm_k(const float* __restrict__ A,
                                              const float* __restrict__ W,
                                              const int* __restrict__ rbeg,
                                              const int* __restrict__ rend,
                                              const int* __restrict__ perm,
                                              const float* __restrict__ tsel,
                                              float* __restrict__ C)
{
    __shared__ float Wl[128 * 160];   // 81920 B
    const int t    = threadIdx.x;
    const int cg   = t & 15;         // 0..15, col base cg*8
    const int rowg = t >> 4;         // 0..31
    const int r0   = (blockIdx.x << 7) + rowg;

    const float* Ap[4];
#pragma unroll
    for (int i = 0; i < 4; ++i) {
        int r = r0 + (i << 5);
        int s = IX ? perm[r] : r;
        Ap[i] = A + ((size_t)s << 7);
    }

    float acc[4][8];
#pragma unroll
    for (int i = 0; i < 4; ++i)
#pragma unroll
        for (int j = 0; j < 8; ++j) acc[i][j] = 0.f;

    // ---- stage ALL of W (4096 float4s, 8 per thread) ----
    {
        const float4* Wg = (const float4*)W;
#pragma unroll
        for (int i = 0; i < 8; ++i) {
            int idx = t + (i << 9);
            int k   = idx >> 5;
            int c4  = (idx & 31) << 2;
            *(float4*)&Wl[k * 160 + (c4 >> 3) * 10 + (c4 & 7)] = Wg[idx];
        }
    }
    float4 xc[4], xn[4];
#pragma unroll
    for (int i = 0; i < 4; ++i) xc[i] = *(const float4*)(Ap[i]);
    __syncthreads();

    const float* wb = &Wl[cg * 10];

#pragma unroll 1
    for (int k0 = 0; k0 < 128; k0 += 4) {
        bool pf = (k0 < 124);
        if (pf) {
#pragma unroll
            for (int i = 0; i < 4; ++i) xn[i] = *(const float4*)(Ap[i] + k0 + 4);
        }
#pragma unroll
        for (int kk = 0; kk < 4; ++kk) {
            const float* wr = wb + (k0 + kk) * 160;
            float wv[8];
            *(float4*)&wv[0] = *(const float4*)(wr);
            *(float4*)&wv[4] = *(const float4*)(wr + 4);
#pragma unroll
            for (int i = 0; i < 4; ++i) {
                float xv = ((const float*)&xc[i])[kk];
#pragma unroll
                for (int j = 0; j < 8; ++j) acc[i][j] = fmaf(xv, wv[j], acc[i][j]);
            }
        }
        if (pf) {
#pragma unroll
            for (int i = 0; i < 4; ++i) xc[i] = xn[i];
        }
    }

    // epilogue: scale by dinv[r] (and tsel[r] if IX), write
#pragma unroll
    for (int i = 0; i < 4; ++i) {
        int r = r0 + (i << 5);
        float deg = (float)(rend[r] - rbeg[r]) + 1.0f;
        float sc = 1.0f / sqrtf(deg);
        if (IX) sc *= tsel[r];
        float* cp = C + ((size_t)r << 7) + (cg << 3);
        float4 v0, v1;
        v0.x = acc[i][0] * sc; v0.y = acc[i][1] * sc; v0.z = acc[i][2] * sc; v0.w = acc[i][3] * sc;
        v1.x = acc[i][4] * sc; v1.y = acc[i][5] * sc; v1.z = acc[i][6] * sc; v1.w = acc[i][7] * sc;
        *(float4*)(cp) = v0;
        *(float4*)(cp + 4) = v1;
    }
}

// ---------------- per-graph CSR build, level 1 (count+scan+fill in one block) ----------
__global__ __launch_bounds__(1024) void build_csr1_k(const int* __restrict__ src, const int* __restrict__ dst,
                                                     int* __restrict__ rbeg, int* __restrict__ rend,
                                                     int* __restrict__ csr)
{
    __shared__ int cnt[NPG];
    int t = threadIdx.x, g = blockIdx.x;
    int ebase = g * EPG;
    cnt[t] = 0;
    __syncthreads();
#pragma unroll
    for (int k = 0; k < EPG / 1024; ++k) {
        int d = dst[ebase + t + k * 1024] & (NPG - 1);
        atomicAdd(&cnt[d], 1);
    }
    __syncthreads();
    int deg0 = cnt[t];
    int val = deg0;
    for (int off = 1; off < NPG; off <<= 1) {
        int u = (t >= off) ? cnt[t - off] : 0;
        __syncthreads();
        val += u; cnt[t] = val;
        __syncthreads();
    }
    int node = g * NPG + t;
    rbeg[node] = ebase + val - deg0;
    rend[node] = ebase + val;
    cnt[t] = val - deg0;
    __syncthreads();
#pragma unroll
    for (int k = 0; k < EPG / 1024; ++k) {
        int e = ebase + t + k * 1024;
        int d = dst[e] & (NPG - 1);
        int pos = atomicAdd(&cnt[d], 1);
        csr[ebase + pos] = src[e];
    }
}

// ---------------- per-graph CSR build, level 2 (prune via nmap, remap ids) -------------
__global__ __launch_bounds__(1024) void build_csr2_k(const int* __restrict__ src, const int* __restrict__ dst,
                                                     const int* __restrict__ nmap,
                                                     int* __restrict__ rbeg, int* __restrict__ rend,
                                                     int* __restrict__ csr)
{
    __shared__ int cnt[K1];
    int t = threadIdx.x, g = blockIdx.x;
    int ebase = g * EPG;
    if (t < K1) cnt[t] = 0;
    __syncthreads();
    int ns[EPG / 1024], nd[EPG / 1024];
#pragma unroll
    for (int k = 0; k < EPG / 1024; ++k) {
        int e = ebase + t + k * 1024;
        ns[k] = nmap[src[e]];
        nd[k] = nmap[dst[e]];
        if (ns[k] >= 0 && nd[k] >= 0) atomicAdd(&cnt[nd[k] & (K1 - 1)], 1);
    }
    __syncthreads();
    int deg0 = 0, val = 0;
    if (t < K1) { deg0 = cnt[t]; val = deg0; }
    for (int off = 1; off < K1; off <<= 1) {
        int u = (t < K1 && t >= off) ? cnt[t - off] : 0;
        __syncthreads();
        if (t < K1) { val += u; cnt[t] = val; }
        __syncthreads();
    }
    if (t < K1) {
        int node = g * K1 + t;
        rbeg[node] = ebase + val - deg0;
        rend[node] = ebase + val;
        cnt[t] = val - deg0;
    }
    __syncthreads();
#pragma unroll
    for (int k = 0; k < EPG / 1024; ++k) {
        if (ns[k] >= 0 && nd[k] >= 0) {
            int pos = atomicAdd(&cnt[nd[k] & (K1 - 1)], 1);
            csr[ebase + pos] = ns[k];
        }
    }
}

// ---------------- GCN aggregation over prescaled rows, fused bias+relu+score-projection ----
// half-wave (32 lanes) per node, float4 per lane; dinv from rbeg/rend; XCD swizzle.
__global__ __launch_bounds__(256) void agg_feat_k(const float4* __restrict__ XWs,
                                                  const int* __restrict__ rbeg, const int* __restrict__ rend,
                                                  const int* __restrict__ csr,
                                                  const float* __restrict__ bias, const float* __restrict__ Ws,
                                                  float* __restrict__ hout, float* __restrict__ hss, int n)
{
    int nblk = gridDim.x;                       // multiple of 8
    int bid  = blockIdx.x;
    int b    = (bid & 7) * (nblk >> 3) + (bid >> 3);   // XCD chunk swizzle
    int half = threadIdx.x >> 5;
    int lane = threadIdx.x & 31;
    int node = (b << 3) + half;
    if (node >= n) return;
    const float4* Xf = XWs + lane;              // row r at Xf[r*32]

    float4 A = make_float4(0.f, 0.f, 0.f, 0.f), B = A, C = A, D = A;
    int p0 = rbeg[node], p1 = rend[node];
    int p = p0;
    for (; p + 8 <= p1; p += 8) {
        int s0 = csr[p], s1 = csr[p + 1], s2 = csr[p + 2], s3 = csr[p + 3];
        int s4 = csr[p + 4], s5 = csr[p + 5], s6 = csr[p + 6], s7 = csr[p + 7];
        float4 v0 = Xf[(size_t)s0 << 5], v1 = Xf[(size_t)s1 << 5];
        float4 v2 = Xf[(size_t)s2 << 5], v3 = Xf[(size_t)s3 << 5];
        float4 v4 = Xf[(size_t)s4 << 5], v5 = Xf[(size_t)s5 << 5];
        float4 v6 = Xf[(size_t)s6 << 5], v7 = Xf[(size_t)s7 << 5];
        A = f4add(A, v0); B = f4add(B, v1); C = f4add(C, v2); D = f4add(D, v3);
        A = f4add(A, v4); B = f4add(B, v5); C = f4add(C, v6); D = f4add(D, v7);
    }
    for (; p + 4 <= p1; p += 4) {
        int s0 = csr[p], s1 = csr[p + 1], s2 = csr[p + 2], s3 = csr[p + 3];
        float4 v0 = Xf[(size_t)s0 << 5], v1 = Xf[(size_t)s1 << 5];
        float4 v2 = Xf[(size_t)s2 << 5], v3 = Xf[(size_t)s3 << 5];
        A = f4add(A, v0); B = f4add(B, v1); C = f4add(C, v2); D = f4add(D, v3);
    }
    for (; p < p1; ++p) {
        int s = csr[p];
        A = f4add(A, Xf[(size_t)s << 5]);
    }
    float4 acc = f4add(f4add(A, B), f4add(C, D));
    acc = f4add(acc, Xf[(size_t)node << 5]);    // self term (prescaled)

    float dd = 1.0f / sqrtf((float)(p1 - p0) + 1.0f);
    float4 bb = *(const float4*)(bias + (lane << 2));
    acc.x = fmaxf(fmaf(acc.x, dd, bb.x), 0.f);
    acc.y = fmaxf(fmaf(acc.y, dd, bb.y), 0.f);
    acc.z = fmaxf(fmaf(acc.z, dd, bb.z), 0.f);
    acc.w = fmaxf(fmaf(acc.w, dd, bb.w), 0.f);
    *(float4*)(hout + ((size_t)node << 7) + (lane << 2)) = acc;

    float4 wsv = *(const float4*)(Ws + (lane << 2));
    float pq = acc.x * wsv.x + acc.y * wsv.y + acc.z * wsv.z + acc.w * wsv.w;
#pragma unroll
    for (int off = 16; off > 0; off >>= 1) pq += __shfl_down(pq, off, 32);
    if (lane == 0) hss[node] = dd * pq;         // prescaled score
}

// ---------------- fused score + per-graph top-k (+ nmap, + tanh(score)) -----------------
template <int NNE, int KK, bool MARK>
__global__ void sctopk_k(const int* __restrict__ rbeg, const int* __restrict__ rend,
                         const int* __restrict__ csr, const float* __restrict__ hss,
                         const float* __restrict__ bsp,
                         int* __restrict__ perm, float* __restrict__ tsel,
                         int* __restrict__ nmap)
{
    __shared__ unsigned long long keys[NNE];
    int t = threadIdx.x, g = blockIdx.x;
    int node = g * NNE + t;
    int p0 = rbeg[node], p1 = rend[node];
    float a = 0.f, b = 0.f, c = 0.f, e = 0.f;
    int p = p0;
    for (; p + 8 <= p1; p += 8) {
        int s0 = csr[p], s1 = csr[p + 1], s2 = csr[p + 2], s3 = csr[p + 3];
        int s4 = csr[p + 4], s5 = csr[p + 5], s6 = csr[p + 6], s7 = csr[p + 7];
        a += hss[s0]; b += hss[s1]; c += hss[s2]; e += hss[s3];
        a += hss[s4]; b += hss[s5]; c += hss[s6]; e += hss[s7];
    }
    for (; p + 4 <= p1; p += 4) {
        int s0 = csr[p], s1 = csr[p + 1], s2 = csr[p + 2], s3 = csr[p + 3];
        a += hss[s0]; b += hss[s1]; c += hss[s2]; e += hss[s3];
    }
    for (; p < p1; ++p) a += hss[csr[p]];
    float dd = 1.0f / sqrtf((float)(p1 - p0) + 1.0f);
    float s = fmaf((a + b) + (c + e) + hss[node], dd, bsp[0]);

    unsigned u = __float_as_uint(s);
    u = (u & 0x80000000u) ? ~u : (u | 0x80000000u);           // monotone map
    keys[t] = (((unsigned long long)u) << 32) | (unsigned)(NNE - 1 - t);
    __syncthreads();
    for (int k = 2; k <= NNE; k <<= 1) {
        for (int j = k >> 1; j > 0; j >>= 1) {
            int ixj = t ^ j;
            if (ixj > t) {
                unsigned long long ka = keys[t], kb = keys[ixj];
                bool up = ((t & k) == 0);
                if ((ka > kb) == up) { keys[t] = kb; keys[ixj] = ka; }
            }
            __syncthreads();
        }
    }
    unsigned long long key = keys[NNE - 1 - t];   // rank t
    int idx = NNE - 1 - (int)(key & 0xFFFFFFFFu);
    if (t < KK) {
        perm[g * KK + t] = g * NNE + idx;
        unsigned uu = (unsigned)(key >> 32);
        float sc = __uint_as_float((uu & 0x80000000u) ? (uu ^ 0x80000000u) : ~uu);
        tsel[g * KK + t] = tanhf(sc);
        if (MARK) nmap[g * NNE + idx] = g * KK + t;
    } else if (MARK) {
        nmap[g * NNE + idx] = -1;
    }
}

// ---------------- readout partials over gathered rows: per-128-node chunk {max | sum} ---
__global__ __launch_bounds__(128) void readout_ix_k(const float* __restrict__ h,
                                                    const int* __restrict__ perm,
                                                    const float* __restrict__ tsel,
                                                    float* __restrict__ part)
{
    int b = blockIdx.x, t = threadIdx.x;
    int base = b * 128;
    float mx = -INFINITY, sm = 0.f;
#pragma unroll 4
    for (int r = 0; r < 128; ++r) {
        int o = perm[base + r];
        float tv = tsel[base + r];
        float v = h[((size_t)o << 7) + t] * tv;
        mx = fmaxf(mx, v);
        sm += v;
    }
    part[b * 256 + t] = mx;
    part[b * 256 + 128 + t] = sm;
}

// ---------------- head: combine partials; z=x1+x2; relu(z@Wl1+bl1); @Wl2+bl2 ------------
__global__ __launch_bounds__(128) void mlp_k(const float* __restrict__ part1, const float* __restrict__ part2,
                                             const float* __restrict__ Wl1, const float* __restrict__ bl1,
                                             const float* __restrict__ Wl2, const float* __restrict__ bl2,
                                             float* __restrict__ out)
{
    __shared__ float z[256];
    __shared__ float red[128];
    int g = blockIdx.x, t = threadIdx.x;
    float mx1 = -INFINITY, sm1 = 0.f;
#pragma unroll
    for (int j = 0; j < 4; ++j) {
        mx1 = fmaxf(mx1, part1[(g * 4 + j) * 256 + t]);
        sm1 += part1[(g * 4 + j) * 256 + 128 + t];
    }
    float mx2 = -INFINITY, sm2 = 0.f;
#pragma unroll
    for (int j = 0; j < 2; ++j) {
        mx2 = fmaxf(mx2, part2[(g * 2 + j) * 256 + t]);
        sm2 += part2[(g * 2 + j) * 256 + 128 + t];
    }
    z[t]       = mx1 + mx2;
    z[t + 128] = sm1 * (1.f / 512.f) + sm2 * (1.f / 256.f);
    __syncthreads();
    float acc = bl1[t];
    for (int k = 0; k < 256; ++k) acc = fmaf(z[k], Wl1[k * 128 + t], acc);
    float zz = fmaxf(acc, 0.f);
    red[t] = zz * Wl2[t];
    __syncthreads();
    for (int off = 64; off > 0; off >>= 1) {
        if (t < off) red[t] += red[t + off];
        __syncthreads();
    }
    if (t == 0) out[g] = red[0] + bl2[0];
}

// ---------------- launch ----------------
extern "C" void kernel_launch(void* const* d_in, const int* in_sizes, int n_in,
                              void* d_out, int out_size, void* d_ws, size_t ws_size,
                              hipStream_t stream)
{
    const float* x   = (const float*)d_in[0];
    const int*   src = (const int*)d_in[1];
    const int*   dst = (const int*)d_in[2];
    const float* W1  = (const float*)d_in[3];
    const float* b1  = (const float*)d_in[4];
    const float* Ws1 = (const float*)d_in[5];
    const float* bs1 = (const float*)d_in[6];
    const float* W2  = (const float*)d_in[7];
    const float* b2  = (const float*)d_in[8];
    const float* Ws2 = (const float*)d_in[9];
    const float* bs2 = (const float*)d_in[10];
    const float* Wl1 = (const float*)d_in[11];
    const float* bl1 = (const float*)d_in[12];
    const float* Wl2 = (const float*)d_in[13];
    const float* bl2 = (const float*)d_in[14];
    float* out = (float*)d_out;
    char* ws = (char*)d_ws;

    // big regions (time-multiplexed)
    float* XW1 = (float*)(ws);                        // 32MB [0,32M)   (dinv-prescaled)
    float* h1  = (float*)(ws + ((size_t)32 << 20));   // 32MB [32M,64M) (alive through readout1)
    float* XW2 = (float*)(ws);                        // 16MB [0,16M)   (XW1 dead after agg1)
    float* h2  = (float*)(ws + ((size_t)16 << 20));   // 16MB [16M,32M)
    size_t SB = (size_t)64 << 20;
    auto alloc = [&](size_t bytes) { char* p = ws + SB; SB += (bytes + 255) & ~(size_t)255; return p; };
    int* csr1     = (int*)alloc((size_t)EE * 4);      // reused as csr2 after sctopk1
    int* rbeg1    = (int*)alloc(NN1 * 4);
    int* rend1    = (int*)alloc(NN1 * 4);
    float* hss1   = (float*)alloc(NN1 * 4);
    int* nmap     = (int*)alloc(NN1 * 4);
    int* perm1    = (int*)alloc(M1 * 4);
    float* tsel1  = (float*)alloc(M1 * 4);
    int* rbeg2    = (int*)alloc(M1 * 4);
    int* rend2    = (int*)alloc(M1 * 4);
    float* hss2   = (float*)alloc(M1 * 4);
    int* perm2    = (int*)alloc(M2 * 4);
    float* tsel2  = (float*)alloc(M2 * 4);
    float* part1  = (float*)alloc(256 * 256 * 4);
    float* part2  = (float*)alloc(128 * 256 * 4);
    int* csr2     = csr1;
    (void)ws_size; (void)in_sizes; (void)n_in; (void)out_size;

    // ---- level 1 ----
    build_csr1_k<<<GG, 1024, 0, stream>>>(src, dst, rbeg1, rend1, csr1);
    gemm_k<false><<<NN1 / 128, 512, 0, stream>>>(x, W1, rbeg1, rend1, nullptr, nullptr, XW1);
    agg_feat_k<<<NN1 / 8, 256, 0, stream>>>((const float4*)XW1, rbeg1, rend1, csr1, b1, Ws1, h1, hss1, NN1);
    sctopk_k<NPG, K1, true><<<GG, NPG, 0, stream>>>(rbeg1, rend1, csr1, hss1, bs1, perm1, tsel1, nmap);
    // ---- level 2 ----
    build_csr2_k<<<GG, 1024, 0, stream>>>(src, dst, nmap, rbeg2, rend2, csr2);
    gemm_k<true><<<M1 / 128, 512, 0, stream>>>(h1, W2, rbeg2, rend2, perm1, tsel1, XW2);
    readout_ix_k<<<M1 / 128, 128, 0, stream>>>(h1, perm1, tsel1, part1);
    agg_feat_k<<<M1 / 8, 256, 0, stream>>>((const float4*)XW2, rbeg2, rend2, csr2, b2, Ws2, h2, hss2, M1);
    sctopk_k<K1, K2, false><<<GG, K1, 0, stream>>>(rbeg2, rend2, csr2, hss2, bs2, perm2, tsel2, nullptr);
    readout_ix_k<<<M2 / 128, 128, 0, stream>>>(h2, perm2, tsel2, part2);
    // ---- head ----
    mlp_k<<<GG, 128, 0, stream>>>(part1, part2, Wl1, bl1, Wl2, bl2, out);
}